// Round 15
// baseline (130.115 us; speedup 1.0000x reference)
//
#include <hip/hip_runtime.h>
#include <hip/hip_bf16.h>

typedef __attribute__((ext_vector_type(4))) float f32x4;
typedef __attribute__((ext_vector_type(8))) __bf16 bf16x8;
typedef __attribute__((ext_vector_type(8))) unsigned short u16x8;

constexpr int BROWS = 4096;   // proteins (output rows)
constexpr int NCOLS = 8192;   // functions (output cols)
constexpr int DK    = 1024;   // inner dim
constexpr int BM = 256, BN = 256, BK = 64;
constexpr int NCB = NCOLS / BN;   // 32 column blocks
constexpr int NKT = DK / BK;      // 16 K-tiles
constexpr int NIT = NKT / 2;      // 8 iterations (2 K-tiles each)

__device__ static inline unsigned short f2bf(float f) {
  unsigned int u = __builtin_bit_cast(unsigned int, f);
  u += 0x7FFFu + ((u >> 16) & 1u);
  return (unsigned short)(u >> 16);
}

__device__ static inline void gload16(const void* g, void* l) {
  __builtin_amdgcn_global_load_lds(
      (const __attribute__((address_space(1))) void*)g,
      (__attribute__((address_space(3))) void*)l, 16, 0, 0);
}

__global__ void convert_kernel(const float* __restrict__ src,
                               unsigned short* __restrict__ dst,
                               int n4, int applyScale,
                               const float* __restrict__ temp) {
  float scale = applyScale ? expf(-temp[0]) : 1.0f;
  int i = blockIdx.x * blockDim.x + threadIdx.x;
  if (i >= n4) return;
  float4 v = reinterpret_cast<const float4*>(src)[i];
  ushort4 o;
  o.x = f2bf(v.x * scale);
  o.y = f2bf(v.y * scale);
  o.z = f2bf(v.z * scale);
  o.w = f2bf(v.w * scale);
  reinterpret_cast<ushort4*>(dst)[i] = o;
}

// stage one 128x64-bf16 half-tile (16 KB): linear LDS dest, T2 swizzle via
// pre-swizzled global source (rule #21; verified 0-conflict R4-R14).
__device__ __forceinline__ void stage_half(const unsigned short* __restrict__ g,
                                           unsigned short* l, int t, int kt) {
#pragma unroll
  for (int p = 0; p < 2; ++p) {
    const int off = p * 8192 + t * 16;        // byte offset within 16KB half buffer
    const int row = off >> 7;                 // 128 B per row (64 bf16)
    const int keSw = ((off & 127) >> 1) ^ ((row & 7) << 3);  // swizzled elem-in-row
    gload16(g + (size_t)row * DK + kt * 64 + keSw, l + (off >> 1));
  }
}

#define MFMA_BF16 __builtin_amdgcn_mfma_f32_16x16x32_bf16

// swizzled read: element index ^ ((row&7)<<3)  <=>  byte ^ ((row&7)<<4)
#define LDS_FRAG(base, row, kk)                                             \
  __builtin_bit_cast(bf16x8, *reinterpret_cast<const u16x8*>(               \
      &(base)[((row) * 64 + (kk) * 32 + l4 * 8) ^ (((row) & 7) << 3)]))

#define READ_A(b, q)                                              \
  aFr[0][0] = LDS_FRAG(As[b][wm], (2*(q)    )*16 + l15, 0);       \
  aFr[0][1] = LDS_FRAG(As[b][wm], (2*(q)    )*16 + l15, 1);       \
  aFr[1][0] = LDS_FRAG(As[b][wm], (2*(q) + 1)*16 + l15, 0);       \
  aFr[1][1] = LDS_FRAG(As[b][wm], (2*(q) + 1)*16 + l15, 1);

#define READ_B(b)                                                 \
  bFr[0][0] = LDS_FRAG(Bs[b][bhB], brB +  0 + l15, 0);            \
  bFr[0][1] = LDS_FRAG(Bs[b][bhB], brB +  0 + l15, 1);            \
  bFr[1][0] = LDS_FRAG(Bs[b][bhB], brB + 16 + l15, 0);            \
  bFr[1][1] = LDS_FRAG(Bs[b][bhB], brB + 16 + l15, 1);            \
  bFr[2][0] = LDS_FRAG(Bs[b][bhB], brB + 32 + l15, 0);            \
  bFr[2][1] = LDS_FRAG(Bs[b][bhB], brB + 32 + l15, 1);            \
  bFr[3][0] = LDS_FRAG(Bs[b][bhB], brB + 48 + l15, 0);            \
  bFr[3][1] = LDS_FRAG(Bs[b][bhB], brB + 48 + l15, 1);

#define COMPUTE(q)                                                                  \
  __builtin_amdgcn_s_setprio(1);                                                   \
  _Pragma("unroll") for (int mm = 0; mm < 2; ++mm)                                  \
  _Pragma("unroll") for (int n = 0; n < 4; ++n) {                                   \
    acc[2*(q)+mm][n] = MFMA_BF16(aFr[mm][0], bFr[n][0], acc[2*(q)+mm][n], 0, 0, 0); \
    acc[2*(q)+mm][n] = MFMA_BF16(aFr[mm][1], bFr[n][1], acc[2*(q)+mm][n], 0, 0, 0); \
  }                                                                                 \
  __builtin_amdgcn_s_setprio(0);

#define PHASE_BAR                          \
  asm volatile("" ::: "memory");           \
  __builtin_amdgcn_s_barrier();            \
  asm volatile("" ::: "memory");

// Pack one 256-col mask row (held as int4/lane) into 4 interleaved u64 words:
// word k holds cols {4l+k} at bit l (R10-verified mapping). lane0 writes 32B.
#define PACKROW(v, row)                                                       \
  {                                                                           \
    unsigned long long b0 = __ballot((v).x == 1);                             \
    unsigned long long b1 = __ballot((v).y == 1);                             \
    unsigned long long b2 = __ballot((v).z == 1);                             \
    unsigned long long b3 = __ballot((v).w == 1);                             \
    if (lane == 0) {                                                          \
      ulonglong4 o; o.x = b0; o.y = b1; o.z = b2; o.w = b3;                   \
      *reinterpret_cast<ulonglong4*>(&lbits[(size_t)(row) * 4]) = o;          \
    }                                                                         \
  }

// 256x256 tile, 8 waves (2Mx4N), BK=64, 8-phase double-buffered, counted
// vmcnt (T4) + setprio (T5) + swizzle (T2), single-barrier phases (R13).
// NEW: in-loop mask pack -- each iteration every wave loads 4 mask rows to
// registers (2 at P1, 2 at P3; +8 VGPR transient, 1-phase liveness) and
// ballot-packs them at P2/P4 into an 8 KB LDS bitmask. Mask HBM traffic
// spreads over the whole K-loop; the epilogue reads ZERO global memory.
__global__ __launch_bounds__(512, 2)
void main_kernel(const unsigned short* __restrict__ Pb,
                 const unsigned short* __restrict__ Fb,
                 const int* __restrict__ mask,
                 f32x4* __restrict__ partials) {
  __shared__ __align__(16) unsigned short As[2][2][128 * 64];  // [buf][half][swizzled]
  __shared__ __align__(16) unsigned short Bs[2][2][128 * 64];
  __shared__ __align__(32) unsigned long long lbits[256 * 4];  // 8 KB bitmask
  __shared__ float redM[4][256], redS[4][256], redP[4][256], redC[4][256];

  const int t    = threadIdx.x;
  const int lane = t & 63;
  const int w    = t >> 6;        // wave 0..7
  const int wm   = w >> 2;        // A half / output row half (0..1)
  const int wn   = w & 3;         // output col quarter (0..3)
  const int l15  = lane & 15;
  const int l4   = lane >> 4;
  const int bhB  = wn >> 1;       // which B half this wave reads
  const int brB  = (wn & 1) * 64; // base row within that B half

  const int brow = blockIdx.y * BM;
  const int bcol = blockIdx.x * BN;

  const unsigned short* Ag0 = Pb + (size_t)brow * DK;
  const unsigned short* Ag1 = Pb + (size_t)(brow + 128) * DK;
  const unsigned short* Bg0 = Fb + (size_t)bcol * DK;
  const unsigned short* Bg1 = Fb + (size_t)(bcol + 128) * DK;

  f32x4 acc[8][4] = {};
  bf16x8 bFr[4][2];
  bf16x8 aFr[2][2];

  // Prologue: stage B(0), A(0), B(1); drain so B(0)+A(0) landed, B(1) in flight.
  stage_half(Bg0, Bs[0][0], t, 0);
  stage_half(Bg1, Bs[0][1], t, 0);
  stage_half(Ag0, As[0][0], t, 0);
  stage_half(Ag1, As[0][1], t, 0);
  stage_half(Bg0, Bs[1][0], t, 1);
  stage_half(Bg1, Bs[1][1], t, 1);
  asm volatile("s_waitcnt vmcnt(4)" ::: "memory");
  PHASE_BAR;

  for (int i = 0; i < NIT; ++i) {
    const int t1 = 2 * i + 1;
    const bool more = (i < NIT - 1);
    const int mr = i * 32 + w;    // this wave's mask-row base for this iter
    // P1: mask rows mr, mr+8 -> regs (issued first = oldest); tile t0 q0; stage A0(t1)
    int4 va0 = reinterpret_cast<const int4*>(mask + (size_t)(brow + mr) * NCOLS + bcol)[lane];
    int4 va1 = reinterpret_cast<const int4*>(mask + (size_t)(brow + mr + 8) * NCOLS + bcol)[lane];
    READ_B(0); READ_A(0, 0);
    stage_half(Ag0, As[1][0], t, t1);
    COMPUTE(0); PHASE_BAR;
    // P2: q1; stage A1(t1); pack mask rows from P1
    READ_A(0, 1);
    stage_half(Ag1, As[1][1], t, t1);
    PACKROW(va0, mr); PACKROW(va1, mr + 8);
    COMPUTE(1); PHASE_BAR;
    // P3: mask rows mr+16, mr+24 -> regs; q2; stage B0(t0+2)
    int4 vb0 = reinterpret_cast<const int4*>(mask + (size_t)(brow + mr + 16) * NCOLS + bcol)[lane];
    int4 vb1 = reinterpret_cast<const int4*>(mask + (size_t)(brow + mr + 24) * NCOLS + bcol)[lane];
    READ_A(0, 2);
    if (more) stage_half(Bg0, Bs[0][0], t, t1 + 1);
    COMPUTE(2); PHASE_BAR;
    // P4: q3; stage B1(t0+2); pack P3 rows; K-tile drain (counted; 0 last iter)
    READ_A(0, 3);
    if (more) stage_half(Bg1, Bs[0][1], t, t1 + 1);
    PACKROW(vb0, mr + 16); PACKROW(vb1, mr + 24);
    COMPUTE(3);
    if (more) { asm volatile("s_waitcnt vmcnt(4)" ::: "memory"); }
    else      { asm volatile("s_waitcnt vmcnt(0)" ::: "memory"); }
    PHASE_BAR;
    // P5: tile t1 q0 (+ all B frags); stage A0(t0+2)
    READ_B(1); READ_A(1, 0);
    if (more) stage_half(Ag0, As[0][0], t, t1 + 1);
    COMPUTE(0); PHASE_BAR;
    // P6: q1; stage A1(t0+2)
    READ_A(1, 1);
    if (more) stage_half(Ag1, As[0][1], t, t1 + 1);
    COMPUTE(1); PHASE_BAR;
    // P7: q2; stage B0(t1+2)
    READ_A(1, 2);
    if (more) stage_half(Bg0, Bs[1][0], t, t1 + 2);
    COMPUTE(2); PHASE_BAR;
    // P8: q3; stage B1(t1+2); K-tile drain
    READ_A(1, 3);
    if (more) stage_half(Bg1, Bs[1][1], t, t1 + 2);
    COMPUTE(3);
    if (more) { asm volatile("s_waitcnt vmcnt(4)" ::: "memory"); }
    PHASE_BAR;
  }

  // Full drain (incl. lgkm for cross-wave lbits visibility) before epilogue.
  __syncthreads();

  // Epilogue: C/D layout col=lane&15, row=(lane>>4)*4+reg (m89-verified).
  // Mask bits from the LDS bitmask: col c = wn*64+16j+l15 -> word l15&3,
  // bit wn*16+(l15>>2)+4j (same formula as R10-R12, which passed).
#pragma unroll
  for (int m = 0; m < 8; ++m) {
#pragma unroll
    for (int r = 0; r < 4; ++r) {
      float v0 = acc[m][0][r], v1 = acc[m][1][r], v2 = acc[m][2][r], v3 = acc[m][3][r];
      float mx = fmaxf(fmaxf(v0, v1), fmaxf(v2, v3));
#pragma unroll
      for (int s = 1; s < 16; s <<= 1) mx = fmaxf(mx, __shfl_xor(mx, s, 64));
      float se = __expf(v0 - mx) + __expf(v1 - mx) + __expf(v2 - mx) + __expf(v3 - mx);

      const int lr = wm * 128 + m * 16 + l4 * 4 + r;
      const unsigned long long wB = lbits[(size_t)lr * 4 + (l15 & 3)];
      const int bsh = wn * 16 + (l15 >> 2);
      float ps = 0.f, pc = 0.f;
      if ((wB >> (bsh     )) & 1ull) { ps += v0; pc += 1.f; }
      if ((wB >> (bsh +  4)) & 1ull) { ps += v1; pc += 1.f; }
      if ((wB >> (bsh +  8)) & 1ull) { ps += v2; pc += 1.f; }
      if ((wB >> (bsh + 12)) & 1ull) { ps += v3; pc += 1.f; }
#pragma unroll
      for (int s = 1; s < 16; s <<= 1) {
        se += __shfl_xor(se, s, 64);
        ps += __shfl_xor(ps, s, 64);
        pc += __shfl_xor(pc, s, 64);
      }
      if (l15 == 0) {
        redM[wn][lr] = mx;
        redS[wn][lr] = se;
        redP[wn][lr] = ps;
        redC[wn][lr] = pc;
      }
    }
  }
  __syncthreads();

  if (t < 256) {
    float m0 = redM[0][t], m1 = redM[1][t], m2 = redM[2][t], m3 = redM[3][t];
    float m  = fmaxf(fmaxf(m0, m1), fmaxf(m2, m3));
    float s  = redS[0][t] * __expf(m0 - m) + redS[1][t] * __expf(m1 - m)
             + redS[2][t] * __expf(m2 - m) + redS[3][t] * __expf(m3 - m);
    float ps = redP[0][t] + redP[1][t] + redP[2][t] + redP[3][t];
    float pc = redC[0][t] + redC[1][t] + redC[2][t] + redC[3][t];
    f32x4 out4;
    out4.x = m; out4.y = s; out4.z = ps; out4.w = pc;
    partials[(size_t)(brow + t) * NCB + blockIdx.x] = out4;
  }
}

// One wave per row: combine the 32 column-block partials -> per-row contribution.
__global__ void row_reduce_kernel(const f32x4* __restrict__ partials,
                                  float* __restrict__ rowContrib,
                                  float* __restrict__ rowCnt) {
  const int row  = blockIdx.x * 4 + (threadIdx.x >> 6);
  const int lane = threadIdx.x & 63;
  f32x4 p = partials[(size_t)row * NCB + (lane & 31)];
  float m = p.x;
#pragma unroll
  for (int s = 1; s < 32; s <<= 1) m = fmaxf(m, __shfl_xor(m, s, 64));
  float se = p.y * __expf(p.x - m);
  float ps = p.z, pc = p.w;
#pragma unroll
  for (int s = 1; s < 32; s <<= 1) {
    se += __shfl_xor(se, s, 64);
    ps += __shfl_xor(ps, s, 64);
    pc += __shfl_xor(pc, s, 64);
  }
  if (lane == 0) {
    float lse = m + logf(se);
    rowContrib[row] = pc * lse - ps;
    rowCnt[row]     = pc;
  }
}

__global__ void final_kernel(const float* __restrict__ rowContrib,
                             const float* __restrict__ rowCnt,
                             float* __restrict__ out) {
  __shared__ double sC[256];
  __shared__ double sN[256];
  double c = 0.0, n = 0.0;
  for (int i = threadIdx.x; i < BROWS; i += 256) {
    c += (double)rowContrib[i];
    n += (double)rowCnt[i];
  }
  sC[threadIdx.x] = c;
  sN[threadIdx.x] = n;
  __syncthreads();
  for (int s = 128; s > 0; s >>= 1) {
    if ((int)threadIdx.x < s) {
      sC[threadIdx.x] += sC[threadIdx.x + s];
      sN[threadIdx.x] += sN[threadIdx.x + s];
    }
    __syncthreads();
  }
  if (threadIdx.x == 0) out[0] = (sN[0] > 0.0) ? (float)(sC[0] / sN[0]) : 0.0f;
}

extern "C" void kernel_launch(void* const* d_in, const int* in_sizes, int n_in,
                              void* d_out, int out_size, void* d_ws, size_t ws_size,
                              hipStream_t stream) {
  const float* P    = (const float*)d_in[0];
  const float* F    = (const float*)d_in[1];
  const int*   mask = (const int*)d_in[2];
  const float* temp = (const float*)d_in[3];
  float* out = (float*)d_out;

  char* ws = (char*)d_ws;
  unsigned short* Pb = (unsigned short*)ws;                              // 8 MB
  unsigned short* Fb = (unsigned short*)(ws + (size_t)BROWS * DK * 2);   // 16 MB
  f32x4* partials    = (f32x4*)(ws + (size_t)(BROWS + NCOLS) * DK * 2);  // 2 MB
  float* rowContrib  = (float*)((char*)partials + (size_t)BROWS * NCB * sizeof(f32x4));
  float* rowCnt      = rowContrib + BROWS;

  const int nP4 = BROWS * DK / 4;
  const int nF4 = NCOLS * DK / 4;
  hipLaunchKernelGGL(convert_kernel, dim3(nP4 / 256), dim3(256), 0, stream, P, Pb, nP4, 1, temp);
  hipLaunchKernelGGL(convert_kernel, dim3(nF4 / 256), dim3(256), 0, stream, F, Fb, nF4, 0, temp);
  hipLaunchKernelGGL(main_kernel, dim3(NCOLS / BN, BROWS / BM), dim3(512), 0, stream, Pb, Fb, mask, partials);
  hipLaunchKernelGGL(row_reduce_kernel, dim3(BROWS / 4), dim3(256), 0, stream, partials, rowContrib, rowCnt);
  hipLaunchKernelGGL(final_kernel, dim3(1), dim3(256), 0, stream, rowContrib, rowCnt, out);
}

// Round 16
// 115.048 us; speedup vs baseline: 1.1310x; 1.1310x over previous
//
#include <hip/hip_runtime.h>
#include <hip/hip_bf16.h>

typedef __attribute__((ext_vector_type(4))) float f32x4;
typedef __attribute__((ext_vector_type(8))) __bf16 bf16x8;
typedef __attribute__((ext_vector_type(8))) unsigned short u16x8;

constexpr int BROWS = 4096;   // proteins (output rows)
constexpr int NCOLS = 8192;   // functions (output cols)
constexpr int DK    = 1024;   // inner dim
constexpr int BM = 256, BN = 256, BK = 64;
constexpr int NCB = NCOLS / BN;   // 32 column blocks
constexpr int NKT = DK / BK;      // 16 K-tiles
constexpr int NIT = NKT / 2;      // 8 iterations (2 K-tiles each)

__device__ static inline unsigned short f2bf(float f) {
  unsigned int u = __builtin_bit_cast(unsigned int, f);
  u += 0x7FFFu + ((u >> 16) & 1u);
  return (unsigned short)(u >> 16);
}

__device__ static inline void gload16(const void* g, void* l) {
  __builtin_amdgcn_global_load_lds(
      (const __attribute__((address_space(1))) void*)g,
      (__attribute__((address_space(3))) void*)l, 16, 0, 0);
}

__global__ void convert_kernel(const float* __restrict__ src,
                               unsigned short* __restrict__ dst,
                               int n4, int applyScale,
                               const float* __restrict__ temp) {
  float scale = applyScale ? expf(-temp[0]) : 1.0f;
  int i = blockIdx.x * blockDim.x + threadIdx.x;
  if (i >= n4) return;
  float4 v = reinterpret_cast<const float4*>(src)[i];
  ushort4 o;
  o.x = f2bf(v.x * scale);
  o.y = f2bf(v.y * scale);
  o.z = f2bf(v.z * scale);
  o.w = f2bf(v.w * scale);
  reinterpret_cast<ushort4*>(dst)[i] = o;
}

// stage one 128x64-bf16 half-tile (16 KB): linear LDS dest, T2 swizzle via
// pre-swizzled global source (rule #21; verified 0-conflict R4-R15).
__device__ __forceinline__ void stage_half(const unsigned short* __restrict__ g,
                                           unsigned short* l, int t, int kt) {
#pragma unroll
  for (int p = 0; p < 2; ++p) {
    const int off = p * 8192 + t * 16;        // byte offset within 16KB half buffer
    const int row = off >> 7;                 // 128 B per row (64 bf16)
    const int keSw = ((off & 127) >> 1) ^ ((row & 7) << 3);  // swizzled elem-in-row
    gload16(g + (size_t)row * DK + kt * 64 + keSw, l + (off >> 1));
  }
}

#define MFMA_BF16 __builtin_amdgcn_mfma_f32_16x16x32_bf16

// swizzled read: element index ^ ((row&7)<<3)  <=>  byte ^ ((row&7)<<4)
#define LDS_FRAG(base, row, kk)                                             \
  __builtin_bit_cast(bf16x8, *reinterpret_cast<const u16x8*>(               \
      &(base)[((row) * 64 + (kk) * 32 + l4 * 8) ^ (((row) & 7) << 3)]))

// read quadrant q's A-frags into a NAMED set (compile-time indexed: rule #20)
#define READ_A_TO(dst, b, q)                                          \
  dst[0][0] = LDS_FRAG(As[b][wm], (2*(q)    )*16 + l15, 0);           \
  dst[0][1] = LDS_FRAG(As[b][wm], (2*(q)    )*16 + l15, 1);           \
  dst[1][0] = LDS_FRAG(As[b][wm], (2*(q) + 1)*16 + l15, 0);           \
  dst[1][1] = LDS_FRAG(As[b][wm], (2*(q) + 1)*16 + l15, 1);

#define READ_B(b)                                                 \
  bFr[0][0] = LDS_FRAG(Bs[b][bhB], brB +  0 + l15, 0);            \
  bFr[0][1] = LDS_FRAG(Bs[b][bhB], brB +  0 + l15, 1);            \
  bFr[1][0] = LDS_FRAG(Bs[b][bhB], brB + 16 + l15, 0);            \
  bFr[1][1] = LDS_FRAG(Bs[b][bhB], brB + 16 + l15, 1);            \
  bFr[2][0] = LDS_FRAG(Bs[b][bhB], brB + 32 + l15, 0);            \
  bFr[2][1] = LDS_FRAG(Bs[b][bhB], brB + 32 + l15, 1);            \
  bFr[3][0] = LDS_FRAG(Bs[b][bhB], brB + 48 + l15, 0);            \
  bFr[3][1] = LDS_FRAG(Bs[b][bhB], brB + 48 + l15, 1);

#define COMPUTE_FROM(src, q)                                                        \
  __builtin_amdgcn_s_setprio(1);                                                   \
  _Pragma("unroll") for (int mm = 0; mm < 2; ++mm)                                  \
  _Pragma("unroll") for (int n = 0; n < 4; ++n) {                                   \
    acc[2*(q)+mm][n] = MFMA_BF16(src[mm][0], bFr[n][0], acc[2*(q)+mm][n], 0, 0, 0); \
    acc[2*(q)+mm][n] = MFMA_BF16(src[mm][1], bFr[n][1], acc[2*(q)+mm][n], 0, 0, 0); \
  }                                                                                 \
  __builtin_amdgcn_s_setprio(0);

#define PHASE_BAR                          \
  asm volatile("" ::: "memory");           \
  __builtin_amdgcn_s_barrier();            \
  asm volatile("" ::: "memory");

// 256x256 tile, 8 waves (2Mx4N), BK=64, 8-phase double-buffered, counted
// vmcnt (T4) + setprio (T5) + swizzle (T2), single-barrier phases (R13).
// NEW: 1-phase A-fragment REGISTER PREFETCH -- each phase issues the NEXT
// quadrant's ds_reads (into the alternate frag set) before computing the
// current one, hiding the LDS epoch under MFMA in 6 of 8 phases. No
// prefetch across buffer-publication boundaries (P4->P5, P8->P1): those
// reads would precede the vmcnt-drain+barrier that publishes the buffer.
__global__ __launch_bounds__(512, 2)
void main_kernel(const unsigned short* __restrict__ Pb,
                 const unsigned short* __restrict__ Fb,
                 const int* __restrict__ mask,
                 f32x4* __restrict__ partials) {
  __shared__ __align__(16) unsigned short As[2][2][128 * 64];  // [buf][half][swizzled]
  __shared__ __align__(16) unsigned short Bs[2][2][128 * 64];
  __shared__ float redM[4][256], redS[4][256], redP[4][256], redC[4][256];

  const int t    = threadIdx.x;
  const int lane = t & 63;
  const int w    = t >> 6;        // wave 0..7
  const int wm   = w >> 2;        // A half / output row half (0..1)
  const int wn   = w & 3;         // output col quarter (0..3)
  const int l15  = lane & 15;
  const int l4   = lane >> 4;
  const int bhB  = wn >> 1;       // which B half this wave reads
  const int brB  = (wn & 1) * 64; // base row within that B half

  const int brow = blockIdx.y * BM;
  const int bcol = blockIdx.x * BN;

  const unsigned short* Ag0 = Pb + (size_t)brow * DK;
  const unsigned short* Ag1 = Pb + (size_t)(brow + 128) * DK;
  const unsigned short* Bg0 = Fb + (size_t)bcol * DK;
  const unsigned short* Bg1 = Fb + (size_t)(bcol + 128) * DK;

  f32x4 acc[8][4] = {};
  bf16x8 bFr[4][2];
  bf16x8 aCur[2][2], aNxt[2][2];

  // Prologue: stage B(0), A(0), B(1); drain so B(0)+A(0) landed, B(1) in flight.
  stage_half(Bg0, Bs[0][0], t, 0);
  stage_half(Bg1, Bs[0][1], t, 0);
  stage_half(Ag0, As[0][0], t, 0);
  stage_half(Ag1, As[0][1], t, 0);
  stage_half(Bg0, Bs[1][0], t, 1);
  stage_half(Bg1, Bs[1][1], t, 1);
  asm volatile("s_waitcnt vmcnt(4)" ::: "memory");
  PHASE_BAR;

  for (int i = 0; i < NIT; ++i) {
    const int t1 = 2 * i + 1;
    const bool more = (i < NIT - 1);
    // P1: own reads (B + q0) + PREFETCH q1; stage A0(t1)
    READ_B(0);
    READ_A_TO(aCur, 0, 0);
    READ_A_TO(aNxt, 0, 1);
    stage_half(Ag0, As[1][0], t, t1);
    COMPUTE_FROM(aCur, 0); PHASE_BAR;
    // P2: PREFETCH q2 into the now-free aCur; stage A1(t1); compute q1
    READ_A_TO(aCur, 0, 2);
    stage_half(Ag1, As[1][1], t, t1);
    COMPUTE_FROM(aNxt, 1); PHASE_BAR;
    // P3: PREFETCH q3; stage B0(t0+2); compute q2
    READ_A_TO(aNxt, 0, 3);
    if (more) stage_half(Bg0, Bs[0][0], t, t1 + 1);
    COMPUTE_FROM(aCur, 2); PHASE_BAR;
    // P4: no prefetch (P5 reads buf1, published only after this drain+bar);
    //     stage B1(t0+2); compute q3; K-tile drain (counted; 0 on last iter)
    if (more) stage_half(Bg1, Bs[0][1], t, t1 + 1);
    COMPUTE_FROM(aNxt, 3);
    if (more) { asm volatile("s_waitcnt vmcnt(4)" ::: "memory"); }
    else      { asm volatile("s_waitcnt vmcnt(0)" ::: "memory"); }
    PHASE_BAR;
    // P5: own reads (B + q0) + PREFETCH q1; stage A0(t0+2)
    READ_B(1);
    READ_A_TO(aCur, 1, 0);
    READ_A_TO(aNxt, 1, 1);
    if (more) stage_half(Ag0, As[0][0], t, t1 + 1);
    COMPUTE_FROM(aCur, 0); PHASE_BAR;
    // P6: PREFETCH q2; stage A1(t0+2); compute q1
    READ_A_TO(aCur, 1, 2);
    if (more) stage_half(Ag1, As[0][1], t, t1 + 1);
    COMPUTE_FROM(aNxt, 1); PHASE_BAR;
    // P7: PREFETCH q3; stage B0(t1+2); compute q2
    READ_A_TO(aNxt, 1, 3);
    if (more) stage_half(Bg0, Bs[1][0], t, t1 + 2);
    COMPUTE_FROM(aCur, 2); PHASE_BAR;
    // P8: no prefetch; stage B1(t1+2); compute q3; K-tile drain
    if (more) stage_half(Bg1, Bs[1][1], t, t1 + 2);
    COMPUTE_FROM(aNxt, 3);
    if (more) { asm volatile("s_waitcnt vmcnt(4)" ::: "memory"); }
    PHASE_BAR;
  }

  // Epilogue: C/D layout col=lane&15, row=(lane>>4)*4+reg (m89-verified).
#pragma unroll
  for (int m = 0; m < 8; ++m) {
#pragma unroll
    for (int r = 0; r < 4; ++r) {
      float v0 = acc[m][0][r], v1 = acc[m][1][r], v2 = acc[m][2][r], v3 = acc[m][3][r];
      float mx = fmaxf(fmaxf(v0, v1), fmaxf(v2, v3));
#pragma unroll
      for (int s = 1; s < 16; s <<= 1) mx = fmaxf(mx, __shfl_xor(mx, s, 64));
      float se = __expf(v0 - mx) + __expf(v1 - mx) + __expf(v2 - mx) + __expf(v3 - mx);

      const int lr = wm * 128 + m * 16 + l4 * 4 + r;
      const int* mrow = mask + (size_t)(brow + lr) * NCOLS + bcol + wn * 64 + l15;
      float ps = 0.f, pc = 0.f;
      if (mrow[0]  == 1) { ps += v0; pc += 1.f; }
      if (mrow[16] == 1) { ps += v1; pc += 1.f; }
      if (mrow[32] == 1) { ps += v2; pc += 1.f; }
      if (mrow[48] == 1) { ps += v3; pc += 1.f; }
#pragma unroll
      for (int s = 1; s < 16; s <<= 1) {
        se += __shfl_xor(se, s, 64);
        ps += __shfl_xor(ps, s, 64);
        pc += __shfl_xor(pc, s, 64);
      }
      if (l15 == 0) {
        redM[wn][lr] = mx;
        redS[wn][lr] = se;
        redP[wn][lr] = ps;
        redC[wn][lr] = pc;
      }
    }
  }
  __syncthreads();

  if (t < 256) {
    float m0 = redM[0][t], m1 = redM[1][t], m2 = redM[2][t], m3 = redM[3][t];
    float m  = fmaxf(fmaxf(m0, m1), fmaxf(m2, m3));
    float s  = redS[0][t] * __expf(m0 - m) + redS[1][t] * __expf(m1 - m)
             + redS[2][t] * __expf(m2 - m) + redS[3][t] * __expf(m3 - m);
    float ps = redP[0][t] + redP[1][t] + redP[2][t] + redP[3][t];
    float pc = redC[0][t] + redC[1][t] + redC[2][t] + redC[3][t];
    f32x4 out4;
    out4.x = m; out4.y = s; out4.z = ps; out4.w = pc;
    partials[(size_t)(brow + t) * NCB + blockIdx.x] = out4;
  }
}

// One wave per row: combine the 32 column-block partials -> per-row contribution.
__global__ void row_reduce_kernel(const f32x4* __restrict__ partials,
                                  float* __restrict__ rowContrib,
                                  float* __restrict__ rowCnt) {
  const int row  = blockIdx.x * 4 + (threadIdx.x >> 6);
  const int lane = threadIdx.x & 63;
  f32x4 p = partials[(size_t)row * NCB + (lane & 31)];
  float m = p.x;
#pragma unroll
  for (int s = 1; s < 32; s <<= 1) m = fmaxf(m, __shfl_xor(m, s, 64));
  float se = p.y * __expf(p.x - m);
  float ps = p.z, pc = p.w;
#pragma unroll
  for (int s = 1; s < 32; s <<= 1) {
    se += __shfl_xor(se, s, 64);
    ps += __shfl_xor(ps, s, 64);
    pc += __shfl_xor(pc, s, 64);
  }
  if (lane == 0) {
    float lse = m + logf(se);
    rowContrib[row] = pc * lse - ps;
    rowCnt[row]     = pc;
  }
}

__global__ void final_kernel(const float* __restrict__ rowContrib,
                             const float* __restrict__ rowCnt,
                             float* __restrict__ out) {
  __shared__ double sC[256];
  __shared__ double sN[256];
  double c = 0.0, n = 0.0;
  for (int i = threadIdx.x; i < BROWS; i += 256) {
    c += (double)rowContrib[i];
    n += (double)rowCnt[i];
  }
  sC[threadIdx.x] = c;
  sN[threadIdx.x] = n;
  __syncthreads();
  for (int s = 128; s > 0; s >>= 1) {
    if ((int)threadIdx.x < s) {
      sC[threadIdx.x] += sC[threadIdx.x + s];
      sN[threadIdx.x] += sN[threadIdx.x + s];
    }
    __syncthreads();
  }
  if (threadIdx.x == 0) out[0] = (sN[0] > 0.0) ? (float)(sC[0] / sN[0]) : 0.0f;
}

extern "C" void kernel_launch(void* const* d_in, const int* in_sizes, int n_in,
                              void* d_out, int out_size, void* d_ws, size_t ws_size,
                              hipStream_t stream) {
  const float* P    = (const float*)d_in[0];
  const float* F    = (const float*)d_in[1];
  const int*   mask = (const int*)d_in[2];
  const float* temp = (const float*)d_in[3];
  float* out = (float*)d_out;

  char* ws = (char*)d_ws;
  unsigned short* Pb = (unsigned short*)ws;                              // 8 MB
  unsigned short* Fb = (unsigned short*)(ws + (size_t)BROWS * DK * 2);   // 16 MB
  f32x4* partials    = (f32x4*)(ws + (size_t)(BROWS + NCOLS) * DK * 2);  // 2 MB
  float* rowContrib  = (float*)((char*)partials + (size_t)BROWS * NCB * sizeof(f32x4));
  float* rowCnt      = rowContrib + BROWS;

  const int nP4 = BROWS * DK / 4;
  const int nF4 = NCOLS * DK / 4;
  hipLaunchKernelGGL(convert_kernel, dim3(nP4 / 256), dim3(256), 0, stream, P, Pb, nP4, 1, temp);
  hipLaunchKernelGGL(convert_kernel, dim3(nF4 / 256), dim3(256), 0, stream, F, Fb, nF4, 0, temp);
  hipLaunchKernelGGL(main_kernel, dim3(NCOLS / BN, BROWS / BM), dim3(512), 0, stream, Pb, Fb, mask, partials);
  hipLaunchKernelGGL(row_reduce_kernel, dim3(BROWS / 4), dim3(256), 0, stream, partials, rowContrib, rowCnt);
  hipLaunchKernelGGL(final_kernel, dim3(1), dim3(256), 0, stream, rowContrib, rowCnt, out);
}